// Round 4
// baseline (69541.425 us; speedup 1.0000x reference)
//
#include <hip/hip_runtime.h>
#include <hip/hip_bf16.h>
#include <math.h>

#define T_ 512
#define B_ 64
#define E_ 256
#define H_ 600
#define G4 2400    // 4*H
#define MTOT 32768 // T*B
#define LDW 2432   // padded WT width (2400 -> 19*128)

// ---------------- generic zero
__global__ __launch_bounds__(256) void zero_kernel(float* __restrict__ p, int n) {
    int i = blockIdx.x * 256 + threadIdx.x;
    if (i < n) p[i] = 0.f;
}

// ---------------- embedding gather: xT[k][m] = embed[us[b,t]*E + k], m = t*64+b
__global__ __launch_bounds__(256) void gather_xT(const int* __restrict__ us,
                                                 const float* __restrict__ embed,
                                                 float* __restrict__ xT) {
    int lane = threadIdx.x & 63;
    int m = blockIdx.x * 64 + lane;
    int b = m & 63, t = m >> 6;
    int tok = us[b * T_ + t];
    for (int k = threadIdx.x >> 6; k < E_; k += 4)
        xT[(size_t)k * MTOT + m] = embed[(size_t)tok * E_ + k];
}

// ---------------- Wc = W1 @ W2  [1200,4], bc = bm1 @ W2 + bm2  [4]
__global__ void wc_kernel(const float* __restrict__ W1, const float* __restrict__ bm1,
                          const float* __restrict__ W2, const float* __restrict__ bm2,
                          float* __restrict__ Wc, float* __restrict__ bc) {
    int idx = blockIdx.x * 256 + threadIdx.x;
    if (idx < 4800) {
        int k = idx >> 2, l = idx & 3;
        float acc = 0.f;
        for (int j = 0; j < 600; ++j) acc += W1[(size_t)k * 600 + j] * W2[j * 4 + l];
        Wc[idx] = acc;
    }
    if (idx < 4) {
        float acc = bm2[idx];
        for (int j = 0; j < 600; ++j) acc += bm1[j] * W2[j * 4 + idx];
        bc[idx] = acc;
    }
}

// ---------------- W [2400][K] -> WT [K][LDW], cols >= 2400 zeroed
__global__ __launch_bounds__(256) void transpose_w(const float* __restrict__ Wf,
                                                   const float* __restrict__ Wb, int K,
                                                   float* __restrict__ WTf,
                                                   float* __restrict__ WTb) {
    __shared__ float t[32][33];
    const float* W = blockIdx.z ? Wb : Wf;
    float* WT = blockIdx.z ? WTb : WTf;
    int n0 = blockIdx.x * 32, k0 = blockIdx.y * 32;
    int j = threadIdx.x & 31, i0 = threadIdx.x >> 5;
#pragma unroll
    for (int r = 0; r < 4; ++r) {
        int i = i0 + r * 8;
        int n = n0 + i, k = k0 + j;
        t[i][j] = (n < G4 && k < K) ? W[(size_t)n * K + k] : 0.f;
    }
    __syncthreads();
#pragma unroll
    for (int r = 0; r < 4; ++r) {
        int i = i0 + r * 8;
        int k = k0 + i;
        if (k < K) WT[(size_t)k * LDW + n0 + j] = t[j][i];
    }
}

// ---------------- fp32 GEMM: pre[n][m] = sum_k AT[k][m_off+m] * WT[k][n]
// grid (LDW/BN, chunkRows/128, 2); z selects direction
#define GBM 128
#define GBK 32
template <int BN>
__global__ __launch_bounds__(256) void gemm_tn(const float* __restrict__ AT, int lda,
                                               int m_offF, int m_offB,
                                               const float* __restrict__ WTf,
                                               const float* __restrict__ WTb, int K,
                                               float* __restrict__ preF,
                                               float* __restrict__ preB, int ldc) {
    constexpr int NF = BN / 16;   // n-fragment per thread
    constexpr int WPT = BN / 32;  // float4 per thread for W staging
    __shared__ float As[GBK][GBM + 4];
    __shared__ float Ws[GBK][BN + 4];
    const float* WT = blockIdx.z ? WTb : WTf;
    float* CT = blockIdx.z ? preB : preF;
    int m_off = blockIdx.z ? m_offB : m_offF;
    int tid = threadIdx.x;
    int n0 = blockIdx.x * BN, m0 = blockIdx.y * GBM;
    int tx = tid & 15, ty = tid >> 4;
    int skk = tid >> 3;
    int scolA = (tid & 7) * 16;
    int scolW = (tid & 7) * (BN / 8);

    float4 ra[4], rw[WPT];
    const float4 z4 = make_float4(0.f, 0.f, 0.f, 0.f);
    {
        bool inK = skk < K;
        const float4* aSrc = (const float4*)(AT + (size_t)skk * lda + m_off + m0 + scolA);
        const float4* wSrc = (const float4*)(WT + (size_t)skk * LDW + n0 + scolW);
#pragma unroll
        for (int r = 0; r < 4; ++r) ra[r] = inK ? aSrc[r] : z4;
#pragma unroll
        for (int r = 0; r < WPT; ++r) rw[r] = inK ? wSrc[r] : z4;
    }

    float acc[NF][8] = {};
    for (int k0 = 0; k0 < K; k0 += GBK) {
        __syncthreads();
#pragma unroll
        for (int r = 0; r < 4; ++r) *(float4*)&As[skk][scolA + 4 * r] = ra[r];
#pragma unroll
        for (int r = 0; r < WPT; ++r) *(float4*)&Ws[skk][scolW + 4 * r] = rw[r];
        __syncthreads();
        int kn = k0 + GBK;
        if (kn < K) {
            bool inK = (kn + skk) < K;
            const float4* aSrc = (const float4*)(AT + (size_t)(kn + skk) * lda + m_off + m0 + scolA);
            const float4* wSrc = (const float4*)(WT + (size_t)(kn + skk) * LDW + n0 + scolW);
#pragma unroll
            for (int r = 0; r < 4; ++r) ra[r] = inK ? aSrc[r] : z4;
#pragma unroll
            for (int r = 0; r < WPT; ++r) rw[r] = inK ? wSrc[r] : z4;
        }
#pragma unroll
        for (int kk = 0; kk < GBK; ++kk) {
            float a[8], w[NF];
            *(float4*)&a[0] = *(float4*)&As[kk][tx * 8];
            *(float4*)&a[4] = *(float4*)&As[kk][tx * 8 + 4];
#pragma unroll
            for (int j = 0; j < NF; j += 4)
                *(float4*)&w[j] = *(float4*)&Ws[kk][ty * NF + j];
#pragma unroll
            for (int j = 0; j < NF; ++j)
#pragma unroll
                for (int i = 0; i < 8; ++i)
                    acc[j][i] = fmaf(w[j], a[i], acc[j][i]);
        }
    }
#pragma unroll
    for (int j = 0; j < NF; ++j) {
        int n = n0 + ty * NF + j;
        if (n < G4) {
            float* dst = CT + (size_t)n * ldc + m0 + tx * 8;
            *(float4*)dst = *(float4*)&acc[j][0];
            *(float4*)(dst + 4) = *(float4*)&acc[j][4];
        }
    }
}

// ---------------- persistent LSTM chunk kernel: runs Tc steps in one launch.
// 150 blocks x 512 threads; blocks 0..74 forward, 75..149 backward;
// wave w handles unit j = (blk%75)*8 + w of its direction.
__global__ __launch_bounds__(512, 1) void lstm_chunk(
    const float* __restrict__ preF, const float* __restrict__ preB, int chunkRows,
    int Tc, int step0,
    const float* __restrict__ WhhF, const float* __restrict__ WhhB,
    const float* __restrict__ bF, const float* __restrict__ bB,
    float* __restrict__ cSt,   // [2][600][64]
    float* __restrict__ hbuf,  // [2 parity][2 dir][600][64]
    float* __restrict__ outF, int o0F, int dF,
    float* __restrict__ outB, int o0B, int dB, int out_ld,
    unsigned* __restrict__ cnt) {
    __shared__ float lh[600 * 64];  // 153.6 KB -> 1 block/CU
    int tid = threadIdx.x;
    int lane = tid & 63;
    int dir = (blockIdx.x >= 75) ? 1 : 0;
    int bb = blockIdx.x - dir * 75;
    int j = __builtin_amdgcn_readfirstlane(bb * 8 + (tid >> 6));

    const float* pre = dir ? preB : preF;
    const float* Whh = dir ? WhhB : WhhF;
    const float* bias = dir ? bB : bF;
    float* outD = dir ? outB : outF;
    int o0 = dir ? o0B : o0F;
    int dcol = dir ? dB : dF;
    unsigned* myCnt = cnt + dir;

    const float4* w0v = (const float4*)(Whh + (size_t)(0 * H_ + j) * H_);
    const float4* w1v = (const float4*)(Whh + (size_t)(1 * H_ + j) * H_);
    const float4* w2v = (const float4*)(Whh + (size_t)(2 * H_ + j) * H_);
    const float4* w3v = (const float4*)(Whh + (size_t)(3 * H_ + j) * H_);

    float bi0 = bias[0 * H_ + j], bi1 = bias[1 * H_ + j];
    float bi2 = bias[2 * H_ + j], bi3 = bias[3 * H_ + j];

    float cval = cSt[(size_t)(dir * H_ + j) * 64 + lane];

    for (int s = 0; s < Tc; ++s) {
        int p = (step0 + s) & 1;
        const float4* src = (const float4*)(hbuf + (size_t)(p * 2 + dir) * H_ * 64);
        __syncthreads();
        {
            float4* dst = (float4*)lh;
            for (int u = tid; u < 9600; u += 512) dst[u] = src[u];
        }
        __syncthreads();

        float a0 = 0.f, a1 = 0.f, a2 = 0.f, a3 = 0.f;
#pragma unroll 4
        for (int q = 0; q < 150; ++q) {
            float4 wa = w0v[q], wb = w1v[q], wc4 = w2v[q], wd = w3v[q];
            const float* pa = (const float*)&wa;
            const float* pb = (const float*)&wb;
            const float* pc = (const float*)&wc4;
            const float* pd = (const float*)&wd;
#pragma unroll
            for (int e = 0; e < 4; ++e) {
                float hv = lh[(q * 4 + e) * 64 + lane];
                a0 = fmaf(hv, pa[e], a0);
                a1 = fmaf(hv, pb[e], a1);
                a2 = fmaf(hv, pc[e], a2);
                a3 = fmaf(hv, pd[e], a3);
            }
        }
        int s_pre = dir ? (Tc - 1 - s) : s;
        int r = s_pre * 64 + lane;
        float gi = pre[(size_t)(0 * H_ + j) * chunkRows + r] + bi0 + a0;
        float gf = pre[(size_t)(1 * H_ + j) * chunkRows + r] + bi1 + a1;
        float gg = pre[(size_t)(2 * H_ + j) * chunkRows + r] + bi2 + a2;
        float go = pre[(size_t)(3 * H_ + j) * chunkRows + r] + bi3 + a3;
        float si = 1.f / (1.f + expf(-gi));
        float sf = 1.f / (1.f + expf(-gf));
        float so = 1.f / (1.f + expf(-go));
        float cn = sf * cval + si * tanhf(gg);
        float hn = so * tanhf(cn);
        cval = cn;

        float* hout = hbuf + (size_t)(((p ^ 1) * 2 + dir) * H_ + j) * 64;
        hout[lane] = hn;
        outD[(size_t)j * out_ld + (o0 + s * dcol) + lane] = hn;

        if (s != Tc - 1) {
            __threadfence();
            __syncthreads();
            if (tid == 0) {
                __hip_atomic_fetch_add(myCnt, 1u, __ATOMIC_ACQ_REL, __HIP_MEMORY_SCOPE_AGENT);
                unsigned target = 75u * (unsigned)(s + 1);
                while (__hip_atomic_load(myCnt, __ATOMIC_ACQUIRE, __HIP_MEMORY_SCOPE_AGENT) < target)
                    __builtin_amdgcn_s_sleep(1);
            }
            __syncthreads();
        }
    }
    cSt[(size_t)(dir * H_ + j) * 64 + lane] = cval;
}

// ---------------- emission accumulate for one chunk of one direction
__global__ __launch_bounds__(256) void emis_add(const float* __restrict__ h1C, int cols,
                                                const float* __restrict__ Wc,
                                                const float* __restrict__ bc, int addBias,
                                                float* __restrict__ ys, int t0) {
    int lane = threadIdx.x & 63;
    int l = __builtin_amdgcn_readfirstlane(threadIdx.x >> 6);
    int tl = blockIdx.x;
    float acc = addBias ? bc[l] : 0.f;
    for (int k = 0; k < H_; ++k)
        acc = fmaf(h1C[(size_t)k * cols + tl * 64 + lane], Wc[k * 4 + l], acc);
    int t = t0 + tl, b = lane;
    ys[((size_t)b * T_ + t) * 4 + l] += acc;
}

// ---------------- CRF log-likelihood per batch
__global__ void crf_fwd(const float* __restrict__ ys, const int* __restrict__ ls,
                        const float* __restrict__ trans, const float* __restrict__ startT,
                        const float* __restrict__ endT, float* __restrict__ llb) {
    int b = blockIdx.x;
    int lane = threadIdx.x;
    float acc = 0.f;
    for (int t = lane; t < T_; t += 64) {
        int tg = ls[b * T_ + t];
        acc += ys[((size_t)b * T_ + t) * 4 + tg];
        if (t > 0) acc += trans[ls[b * T_ + t - 1] * 4 + tg];
    }
    for (int off = 32; off; off >>= 1) acc += __shfl_down(acc, off);
    float num = 0.f;
    if (lane == 0) num = startT[ls[b * T_]] + acc + endT[ls[b * T_ + T_ - 1]];

    float a = -1e30f;
    if (lane < 4) a = startT[lane] + ys[((size_t)b * T_) * 4 + lane];
    for (int t = 1; t < T_; ++t) {
        float a0 = __shfl(a, 0), a1 = __shfl(a, 1), a2 = __shfl(a, 2), a3 = __shfl(a, 3);
        if (lane < 4) {
            float v0 = a0 + trans[0 * 4 + lane];
            float v1 = a1 + trans[1 * 4 + lane];
            float v2 = a2 + trans[2 * 4 + lane];
            float v3 = a3 + trans[3 * 4 + lane];
            float mx = fmaxf(fmaxf(v0, v1), fmaxf(v2, v3));
            float ssum = expf(v0 - mx) + expf(v1 - mx) + expf(v2 - mx) + expf(v3 - mx);
            a = mx + logf(ssum) + ys[((size_t)b * T_ + t) * 4 + lane];
        }
    }
    float a0 = __shfl(a, 0), a1 = __shfl(a, 1), a2 = __shfl(a, 2), a3 = __shfl(a, 3);
    if (lane == 0) {
        float v0 = a0 + endT[0], v1 = a1 + endT[1], v2 = a2 + endT[2], v3 = a3 + endT[3];
        float mx = fmaxf(fmaxf(v0, v1), fmaxf(v2, v3));
        float den = mx + logf(expf(v0 - mx) + expf(v1 - mx) + expf(v2 - mx) + expf(v3 - mx));
        llb[b] = num - den;
    }
}

__global__ void final_loss(const float* __restrict__ llb, float* __restrict__ out) {
    int lane = threadIdx.x;
    float v = llb[lane];
    for (int off = 32; off; off >>= 1) v += __shfl_down(v, off);
    if (lane == 0) out[0] = -v / 64.0f;
}

// ---------------- Viterbi decode (tags written as float at out[1..])
__global__ void viterbi(const float* __restrict__ ys, const float* __restrict__ trans,
                        const float* __restrict__ startT, const float* __restrict__ endT,
                        float* __restrict__ out) {
    __shared__ unsigned char bp[T_ * 4];
    int b = blockIdx.x;
    int lane = threadIdx.x;
    float a = -1e30f;
    if (lane < 4) a = startT[lane] + ys[((size_t)b * T_) * 4 + lane];
    for (int t = 1; t < T_; ++t) {
        float a0 = __shfl(a, 0), a1 = __shfl(a, 1), a2 = __shfl(a, 2), a3 = __shfl(a, 3);
        if (lane < 4) {
            float av[4] = {a0, a1, a2, a3};
            float best = av[0] + trans[lane];
            int bi = 0;
            for (int lp = 1; lp < 4; ++lp) {
                float v = av[lp] + trans[lp * 4 + lane];
                if (v > best) { best = v; bi = lp; }
            }
            bp[t * 4 + lane] = (unsigned char)bi;
            a = best + ys[((size_t)b * T_ + t) * 4 + lane];
        }
    }
    float a0 = __shfl(a, 0), a1 = __shfl(a, 1), a2 = __shfl(a, 2), a3 = __shfl(a, 3);
    if (lane == 0) {
        float v[4] = {a0 + endT[0], a1 + endT[1], a2 + endT[2], a3 + endT[3]};
        int tag = 0;
        float best = v[0];
        for (int l = 1; l < 4; ++l)
            if (v[l] > best) { best = v[l]; tag = l; }
        out[1 + b * T_ + (T_ - 1)] = (float)tag;
        for (int t = T_ - 1; t >= 1; --t) {
            tag = bp[t * 4 + tag];
            out[1 + b * T_ + t - 1] = (float)tag;
        }
    }
}

extern "C" void kernel_launch(void* const* d_in, const int* in_sizes, int n_in,
                              void* d_out, int out_size, void* d_ws, size_t ws_size,
                              hipStream_t stream) {
    const int* us = (const int*)d_in[0];
    const int* ls = (const int*)d_in[1];
    const float* embed = (const float*)d_in[2];
    const float* Wih0f = (const float*)d_in[3];
    const float* Whh0f = (const float*)d_in[4];
    const float* b0f   = (const float*)d_in[5];
    const float* Wih0b = (const float*)d_in[6];
    const float* Whh0b = (const float*)d_in[7];
    const float* b0b   = (const float*)d_in[8];
    const float* Wih1f = (const float*)d_in[9];
    const float* Whh1f = (const float*)d_in[10];
    const float* b1f   = (const float*)d_in[11];
    const float* Wih1b = (const float*)d_in[12];
    const float* Whh1b = (const float*)d_in[13];
    const float* b1b   = (const float*)d_in[14];
    const float* W1    = (const float*)d_in[15];
    const float* bm1   = (const float*)d_in[16];
    const float* W2    = (const float*)d_in[17];
    const float* bm2   = (const float*)d_in[18];
    const float* trans = (const float*)d_in[19];
    const float* startT= (const float*)d_in[20];
    const float* endT  = (const float*)d_in[21];
    float* out = (float*)d_out;

    char* p = (char*)d_ws;
    auto alloc = [&](size_t bytes) {
        char* r = p;
        p += (bytes + 255) & ~(size_t)255;
        return r;
    };
    float* xT  = (float*)alloc((size_t)E_ * MTOT * 4);        // 33.5 MB
    float* h0T = (float*)alloc((size_t)1200 * MTOT * 4);      // 157 MB
    float* states = (float*)alloc((size_t)6 * H_ * 64 * 4);   // c[2]+hbuf[4]
    unsigned* cnt = (unsigned*)alloc(256);
    float* Wc  = (float*)alloc(4800 * 4);
    float* bc  = (float*)alloc(4 * 4);
    float* ysb = (float*)alloc((size_t)B_ * T_ * 4 * 4);      // 2 MB
    float* llb = (float*)alloc(64 * 4);
    float* WT0f = (float*)alloc((size_t)E_ * LDW * 4);
    float* WT0b = (float*)alloc((size_t)E_ * LDW * 4);
    float* WT1f = (float*)alloc((size_t)1200 * LDW * 4);
    float* WT1b = (float*)alloc((size_t)1200 * LDW * 4);

    size_t used = (size_t)(p - (char*)d_ws);
    size_t perTc = (size_t)2 * G4 * 64 * 4 + (size_t)2 * H_ * 64 * 4;
    int Tc = 128;
    while (Tc > 8 && used + (size_t)Tc * perTc + 4096 > ws_size) Tc >>= 1;
    float* preF = (float*)alloc((size_t)G4 * Tc * 64 * 4);
    float* preB = (float*)alloc((size_t)G4 * Tc * 64 * 4);
    float* h1fC = (float*)alloc((size_t)H_ * Tc * 64 * 4);
    float* h1bC = (float*)alloc((size_t)H_ * Tc * 64 * 4);
    int nc = T_ / Tc;
    int chunkRows = Tc * 64;

    gather_xT<<<MTOT / 64, 256, 0, stream>>>(us, embed, xT);
    wc_kernel<<<19, 256, 0, stream>>>(W1, bm1, W2, bm2, Wc, bc);
    zero_kernel<<<(B_ * T_ * 4 + 255) / 256, 256, 0, stream>>>(ysb, B_ * T_ * 4);
    transpose_w<<<dim3(LDW / 32, E_ / 32, 2), 256, 0, stream>>>(Wih0f, Wih0b, E_, WT0f, WT0b);
    transpose_w<<<dim3(LDW / 32, (1200 + 31) / 32, 2), 256, 0, stream>>>(Wih1f, Wih1b, 1200, WT1f, WT1b);

    float* cSt  = states;                 // [2][600][64]
    float* hbuf = states + 2 * H_ * 64;   // [2][2][600][64]

    int useBN128 = (chunkRows >= 8192);

    for (int layer = 0; layer < 2; ++layer) {
        const float* AT = layer ? h0T : xT;
        int K = layer ? 1200 : 256;
        const float* WTf = layer ? WT1f : WT0f;
        const float* WTb = layer ? WT1b : WT0b;
        const float* WhF = layer ? Whh1f : Whh0f;
        const float* WhB = layer ? Whh1b : Whh0b;
        const float* bF  = layer ? b1f : b0f;
        const float* bB  = layer ? b1b : b0b;

        zero_kernel<<<(6 * H_ * 64 + 255) / 256, 256, 0, stream>>>(states, 6 * H_ * 64);

        for (int c = 0; c < nc; ++c) {
            int moffF = c * Tc * 64;
            int moffB = (T_ - (c + 1) * Tc) * 64;
            if (useBN128) {
                dim3 gg(LDW / 128, chunkRows / GBM, 2);
                gemm_tn<128><<<gg, 256, 0, stream>>>(AT, MTOT, moffF, moffB, WTf, WTb, K,
                                                     preF, preB, chunkRows);
            } else {
                dim3 gg(LDW / 64, chunkRows / GBM, 2);
                gemm_tn<64><<<gg, 256, 0, stream>>>(AT, MTOT, moffF, moffB, WTf, WTb, K,
                                                    preF, preB, chunkRows);
            }
            zero_kernel<<<1, 256, 0, stream>>>((float*)cnt, 2);

            int step0 = c * Tc;
            float* outF; int o0F, dF; float* outB; int o0B, dB; int oldd;
            if (layer == 0) {
                outF = h0T;                        o0F = step0 * 64;            dF = 64;
                outB = h0T + (size_t)H_ * MTOT;    o0B = (T_ - 1 - step0) * 64; dB = -64;
                oldd = MTOT;
            } else {
                outF = h1fC;                       o0F = 0;                     dF = 64;
                outB = h1bC;                       o0B = (Tc - 1) * 64;         dB = -64;
                oldd = chunkRows;
            }
            lstm_chunk<<<150, 512, 0, stream>>>(preF, preB, chunkRows, Tc, step0,
                                                WhF, WhB, bF, bB, cSt, hbuf,
                                                outF, o0F, dF, outB, o0B, dB, oldd, cnt);
            if (layer == 1) {
                emis_add<<<Tc, 256, 0, stream>>>(h1fC, chunkRows, Wc, bc, 1, ysb, c * Tc);
                emis_add<<<Tc, 256, 0, stream>>>(h1bC, chunkRows, Wc + 600 * 4, bc, 0, ysb,
                                                 T_ - (c + 1) * Tc);
            }
        }
    }

    crf_fwd<<<B_, 64, 0, stream>>>(ysb, ls, trans, startT, endT, llb);
    final_loss<<<1, 64, 0, stream>>>(llb, out);
    viterbi<<<B_, 64, 0, stream>>>(ysb, trans, startT, endT, out);
}

// Round 5
// 27753.778 us; speedup vs baseline: 2.5057x; 2.5057x over previous
//
#include <hip/hip_runtime.h>
#include <hip/hip_bf16.h>
#include <math.h>

#define T_ 512
#define B_ 64
#define E_ 256
#define H_ 600
#define G4 2400    // 4*H
#define MTOT 32768 // T*B
#define NP 2432    // padded gate rows (19*128)
#define KP1 1216   // padded K for layer 1 (38*32)

typedef __attribute__((ext_vector_type(8))) short bf16x8;
typedef __attribute__((ext_vector_type(4))) float f32x4;

static __device__ __forceinline__ ushort f2bf(float x) {
    unsigned u = __builtin_bit_cast(unsigned, x);
    unsigned r = (u + 0x7FFFu + ((u >> 16) & 1u)) >> 16;
    return (ushort)r;
}
static __device__ __forceinline__ float bf2f(ushort h) {
    unsigned u = ((unsigned)h) << 16;
    return __builtin_bit_cast(float, u);
}

// ---------------- generic zero
__global__ __launch_bounds__(256) void zero_kernel(float* __restrict__ p, int n) {
    int i = blockIdx.x * 256 + threadIdx.x;
    if (i < n) p[i] = 0.f;
}

// ---------------- embedding gather + bf16 split: xsp[m][k], m = t*64+b
__global__ __launch_bounds__(256) void xsplit(const int* __restrict__ us,
                                              const float* __restrict__ embed,
                                              ushort* __restrict__ xh,
                                              ushort* __restrict__ xl) {
    int m = blockIdx.x;
    int t = m >> 6, b = m & 63;
    int tok = us[b * T_ + t];
    int k = threadIdx.x;
    float v = embed[(size_t)tok * E_ + k];
    ushort hi = f2bf(v);
    xh[(size_t)m * E_ + k] = hi;
    xl[(size_t)m * E_ + k] = f2bf(v - bf2f(hi));
}

// ---------------- weight bf16 split: W[2400][K] -> [NP][Kp] hi/lo, padded zero
__global__ __launch_bounds__(256) void wsplit(const float* __restrict__ Wf,
                                              const float* __restrict__ Wb, int K, int Kp,
                                              ushort* __restrict__ whF, ushort* __restrict__ wlF,
                                              ushort* __restrict__ whB, ushort* __restrict__ wlB) {
    const float* W = blockIdx.z ? Wb : Wf;
    ushort* wh = blockIdx.z ? whB : whF;
    ushort* wl = blockIdx.z ? wlB : wlF;
    int n = blockIdx.x;
    for (int k = threadIdx.x; k < Kp; k += 256) {
        float v = (n < G4 && k < K) ? W[(size_t)n * K + k] : 0.f;
        ushort hi = f2bf(v);
        wh[(size_t)n * Kp + k] = hi;
        wl[(size_t)n * Kp + k] = f2bf(v - bf2f(hi));
    }
}

// ---------------- zero pad columns 1200..1215 of h0sp
__global__ __launch_bounds__(256) void padzero(ushort* __restrict__ h, ushort* __restrict__ l) {
    int idx = blockIdx.x * 256 + threadIdx.x;
    int m = idx >> 4, c = 1200 + (idx & 15);
    h[(size_t)m * KP1 + c] = 0;
    l[(size_t)m * KP1 + c] = 0;
}

// ---------------- Wc = W1 @ W2  [1200,4], bc = bm1 @ W2 + bm2  [4]
__global__ void wc_kernel(const float* __restrict__ W1, const float* __restrict__ bm1,
                          const float* __restrict__ W2, const float* __restrict__ bm2,
                          float* __restrict__ Wc, float* __restrict__ bc) {
    int idx = blockIdx.x * 256 + threadIdx.x;
    if (idx < 4800) {
        int k = idx >> 2, l = idx & 3;
        float acc = 0.f;
        for (int j = 0; j < 600; ++j) acc += W1[(size_t)k * 600 + j] * W2[j * 4 + l];
        Wc[idx] = acc;
    }
    if (idx < 4) {
        float acc = bm2[idx];
        for (int j = 0; j < 600; ++j) acc += bm1[j] * W2[j * 4 + idx];
        bc[idx] = acc;
    }
}

// ---------------- split-bf16 MFMA GEMM: pre[n][m] = sum_k W[n][k] * act[m][k]
// grid (NP/128, chunkRows/128, 2 dirs), 256 threads (4 waves, 2x2 of 64x64)
__global__ __launch_bounds__(256) void gemm_mfma(
    const ushort* __restrict__ WhF, const ushort* __restrict__ WlF,
    const ushort* __restrict__ WhB, const ushort* __restrict__ WlB,
    const ushort* __restrict__ actH, const ushort* __restrict__ actL,
    int Kp, int m_offF, int m_offB,
    float* __restrict__ preF, float* __restrict__ preB, int ldc) {
    __shared__ __align__(16) ushort WsH[128][40];
    __shared__ __align__(16) ushort WsL[128][40];
    __shared__ __align__(16) ushort AsH[128][40];
    __shared__ __align__(16) ushort AsL[128][40];
    const ushort* Wh = blockIdx.z ? WhB : WhF;
    const ushort* Wl = blockIdx.z ? WlB : WlF;
    float* pre = blockIdx.z ? preB : preF;
    int m_off = blockIdx.z ? m_offB : m_offF;
    int n0 = blockIdx.x * 128, m0 = blockIdx.y * 128;
    int tid = threadIdx.x, lane = tid & 63, w = tid >> 6;
    int wn = (w >> 1) * 64, wm = (w & 1) * 64;
    int r0 = tid >> 2;         // 0..63
    int kg = (tid & 3) * 8;    // 0,8,16,24
    int fr = lane & 15, kb = (lane >> 4) * 8;

    f32x4 acc[4][4] = {};

    for (int ks = 0; ks < Kp; ks += 32) {
        __syncthreads();
#pragma unroll
        for (int c = 0; c < 2; ++c) {
            int row = r0 + c * 64;
            size_t go = (size_t)(n0 + row) * Kp + ks + kg;
            *(uint4*)&WsH[row][kg] = *(const uint4*)&Wh[go];
            *(uint4*)&WsL[row][kg] = *(const uint4*)&Wl[go];
            size_t ga = (size_t)(m_off + m0 + row) * Kp + ks + kg;
            *(uint4*)&AsH[row][kg] = *(const uint4*)&actH[ga];
            *(uint4*)&AsL[row][kg] = *(const uint4*)&actL[ga];
        }
        __syncthreads();

        bf16x8 ah[4], al[4], bh[4], bl[4];
#pragma unroll
        for (int i = 0; i < 4; ++i) {
            ah[i] = *(const bf16x8*)&WsH[wn + i * 16 + fr][kb];
            al[i] = *(const bf16x8*)&WsL[wn + i * 16 + fr][kb];
            bh[i] = *(const bf16x8*)&AsH[wm + i * 16 + fr][kb];
            bl[i] = *(const bf16x8*)&AsL[wm + i * 16 + fr][kb];
        }
#pragma unroll
        for (int i = 0; i < 4; ++i)
#pragma unroll
            for (int j = 0; j < 4; ++j) {
                acc[i][j] = __builtin_amdgcn_mfma_f32_16x16x32_bf16(ah[i], bh[j], acc[i][j], 0, 0, 0);
                acc[i][j] = __builtin_amdgcn_mfma_f32_16x16x32_bf16(ah[i], bl[j], acc[i][j], 0, 0, 0);
                acc[i][j] = __builtin_amdgcn_mfma_f32_16x16x32_bf16(al[i], bh[j], acc[i][j], 0, 0, 0);
            }
    }

    int fq = lane >> 4;
#pragma unroll
    for (int i = 0; i < 4; ++i) {
        int nbase = n0 + wn + i * 16 + fq * 4;
#pragma unroll
        for (int j = 0; j < 4; ++j) {
            int m = m0 + wm + j * 16 + fr;
#pragma unroll
            for (int r = 0; r < 4; ++r) {
                int n = nbase + r;
                if (n < G4) pre[(size_t)n * ldc + m] = acc[i][j][r];
            }
        }
    }
}

// ---------------- one LSTM time step, both directions (round-3 proven version
// + optional bf16 split store for layer 0)
__global__ __launch_bounds__(256) void lstm_step(
    const float* __restrict__ preF, const float* __restrict__ preB, int pre_ld,
    int sF, int sB,
    const float* __restrict__ WhhF, const float* __restrict__ WhhB,
    const float* __restrict__ biasF, const float* __restrict__ biasB,
    const float* __restrict__ hInF, float* __restrict__ hOutF, float* __restrict__ cF,
    const float* __restrict__ hInB, float* __restrict__ hOutB, float* __restrict__ cB,
    float* __restrict__ outF, int colF, float* __restrict__ outB, int colB, int out_ld,
    ushort* __restrict__ spH, ushort* __restrict__ spL) {
    __shared__ float lh[120 * 64];
    int tid = threadIdx.x;
    int lane = tid & 63;
    int dir = (blockIdx.x >= 150) ? 1 : 0;
    int jb = blockIdx.x - dir * 150;
    int j = __builtin_amdgcn_readfirstlane(jb * 4 + (tid >> 6));
    const float* pre = dir ? preB : preF;
    const float* Whh = dir ? WhhB : WhhF;
    const float* bias = dir ? biasB : biasF;
    const float* hIn = dir ? hInB : hInF;
    float* hOut = dir ? hOutB : hOutF;
    float* cSt = dir ? cB : cF;
    float* outD = dir ? outB : outF;
    int s = dir ? sB : sF;
    int col = dir ? colB : colF;

    const float4* w0v = (const float4*)(Whh + (size_t)(0 * H_ + j) * H_);
    const float4* w1v = (const float4*)(Whh + (size_t)(1 * H_ + j) * H_);
    const float4* w2v = (const float4*)(Whh + (size_t)(2 * H_ + j) * H_);
    const float4* w3v = (const float4*)(Whh + (size_t)(3 * H_ + j) * H_);

    float a0 = 0.f, a1 = 0.f, a2 = 0.f, a3 = 0.f;
    for (int k0 = 0; k0 < H_; k0 += 120) {
        __syncthreads();
        {
            const float4* src = (const float4*)(hIn + (size_t)k0 * 64);
            float4* dst = (float4*)lh;
            for (int u = tid; u < 1920; u += 256) dst[u] = src[u];
        }
        __syncthreads();
        int q0 = k0 >> 2;
#pragma unroll
        for (int q = 0; q < 30; ++q) {
            float4 wa = w0v[q0 + q], wb = w1v[q0 + q], wc = w2v[q0 + q], wd = w3v[q0 + q];
            const float* pa = (const float*)&wa;
            const float* pb = (const float*)&wb;
            const float* pc = (const float*)&wc;
            const float* pd = (const float*)&wd;
#pragma unroll
            for (int e = 0; e < 4; ++e) {
                float hv = lh[(q * 4 + e) * 64 + lane];
                a0 = fmaf(hv, pa[e], a0);
                a1 = fmaf(hv, pb[e], a1);
                a2 = fmaf(hv, pc[e], a2);
                a3 = fmaf(hv, pd[e], a3);
            }
        }
    }
    int r = s * 64 + lane;
    float gi = pre[(size_t)(0 * H_ + j) * pre_ld + r] + bias[0 * H_ + j] + a0;
    float gf = pre[(size_t)(1 * H_ + j) * pre_ld + r] + bias[1 * H_ + j] + a1;
    float gg = pre[(size_t)(2 * H_ + j) * pre_ld + r] + bias[2 * H_ + j] + a2;
    float go = pre[(size_t)(3 * H_ + j) * pre_ld + r] + bias[3 * H_ + j] + a3;
    float co = cSt[j * 64 + lane];
    float si = 1.f / (1.f + expf(-gi));
    float sf = 1.f / (1.f + expf(-gf));
    float so = 1.f / (1.f + expf(-go));
    float cn = sf * co + si * tanhf(gg);
    float hn = so * tanhf(cn);
    cSt[j * 64 + lane] = cn;
    hOut[j * 64 + lane] = hn;
    if (spH) {
        int m = col + lane;                 // col = t*64 (global)
        int cc = dir ? (600 + j) : j;
        ushort hi = f2bf(hn);
        spH[(size_t)m * KP1 + cc] = hi;
        spL[(size_t)m * KP1 + cc] = f2bf(hn - bf2f(hi));
    } else {
        outD[(size_t)j * out_ld + col + lane] = hn;
    }
}

// ---------------- emission accumulate for one chunk of one direction
__global__ __launch_bounds__(256) void emis_add(const float* __restrict__ h1C, int cols,
                                                const float* __restrict__ Wc,
                                                const float* __restrict__ bc, int addBias,
                                                float* __restrict__ ys, int t0) {
    int lane = threadIdx.x & 63;
    int l = __builtin_amdgcn_readfirstlane(threadIdx.x >> 6);
    int tl = blockIdx.x;
    float acc = addBias ? bc[l] : 0.f;
    for (int k = 0; k < H_; ++k)
        acc = fmaf(h1C[(size_t)k * cols + tl * 64 + lane], Wc[k * 4 + l], acc);
    int t = t0 + tl, b = lane;
    ys[((size_t)b * T_ + t) * 4 + l] += acc;
}

// ---------------- CRF log-likelihood per batch
__global__ void crf_fwd(const float* __restrict__ ys, const int* __restrict__ ls,
                        const float* __restrict__ trans, const float* __restrict__ startT,
                        const float* __restrict__ endT, float* __restrict__ llb) {
    int b = blockIdx.x;
    int lane = threadIdx.x;
    float acc = 0.f;
    for (int t = lane; t < T_; t += 64) {
        int tg = ls[b * T_ + t];
        acc += ys[((size_t)b * T_ + t) * 4 + tg];
        if (t > 0) acc += trans[ls[b * T_ + t - 1] * 4 + tg];
    }
    for (int off = 32; off; off >>= 1) acc += __shfl_down(acc, off);
    float num = 0.f;
    if (lane == 0) num = startT[ls[b * T_]] + acc + endT[ls[b * T_ + T_ - 1]];

    float a = -1e30f;
    if (lane < 4) a = startT[lane] + ys[((size_t)b * T_) * 4 + lane];
    for (int t = 1; t < T_; ++t) {
        float a0 = __shfl(a, 0), a1 = __shfl(a, 1), a2 = __shfl(a, 2), a3 = __shfl(a, 3);
        if (lane < 4) {
            float v0 = a0 + trans[0 * 4 + lane];
            float v1 = a1 + trans[1 * 4 + lane];
            float v2 = a2 + trans[2 * 4 + lane];
            float v3 = a3 + trans[3 * 4 + lane];
            float mx = fmaxf(fmaxf(v0, v1), fmaxf(v2, v3));
            float ssum = expf(v0 - mx) + expf(v1 - mx) + expf(v2 - mx) + expf(v3 - mx);
            a = mx + logf(ssum) + ys[((size_t)b * T_ + t) * 4 + lane];
        }
    }
    float a0 = __shfl(a, 0), a1 = __shfl(a, 1), a2 = __shfl(a, 2), a3 = __shfl(a, 3);
    if (lane == 0) {
        float v0 = a0 + endT[0], v1 = a1 + endT[1], v2 = a2 + endT[2], v3 = a3 + endT[3];
        float mx = fmaxf(fmaxf(v0, v1), fmaxf(v2, v3));
        float den = mx + logf(expf(v0 - mx) + expf(v1 - mx) + expf(v2 - mx) + expf(v3 - mx));
        llb[b] = num - den;
    }
}

__global__ void final_loss(const float* __restrict__ llb, float* __restrict__ out) {
    int lane = threadIdx.x;
    float v = llb[lane];
    for (int off = 32; off; off >>= 1) v += __shfl_down(v, off);
    if (lane == 0) out[0] = -v / 64.0f;
}

// ---------------- Viterbi decode (tags written as float at out[1..])
__global__ void viterbi(const float* __restrict__ ys, const float* __restrict__ trans,
                        const float* __restrict__ startT, const float* __restrict__ endT,
                        float* __restrict__ out) {
    __shared__ unsigned char bp[T_ * 4];
    int b = blockIdx.x;
    int lane = threadIdx.x;
    float a = -1e30f;
    if (lane < 4) a = startT[lane] + ys[((size_t)b * T_) * 4 + lane];
    for (int t = 1; t < T_; ++t) {
        float a0 = __shfl(a, 0), a1 = __shfl(a, 1), a2 = __shfl(a, 2), a3 = __shfl(a, 3);
        if (lane < 4) {
            float av[4] = {a0, a1, a2, a3};
            float best = av[0] + trans[lane];
            int bi = 0;
            for (int lp = 1; lp < 4; ++lp) {
                float v = av[lp] + trans[lp * 4 + lane];
                if (v > best) { best = v; bi = lp; }
            }
            bp[t * 4 + lane] = (unsigned char)bi;
            a = best + ys[((size_t)b * T_ + t) * 4 + lane];
        }
    }
    float a0 = __shfl(a, 0), a1 = __shfl(a, 1), a2 = __shfl(a, 2), a3 = __shfl(a, 3);
    if (lane == 0) {
        float v[4] = {a0 + endT[0], a1 + endT[1], a2 + endT[2], a3 + endT[3]};
        int tag = 0;
        float best = v[0];
        for (int l = 1; l < 4; ++l)
            if (v[l] > best) { best = v[l]; tag = l; }
        out[1 + b * T_ + (T_ - 1)] = (float)tag;
        for (int t = T_ - 1; t >= 1; --t) {
            tag = bp[t * 4 + tag];
            out[1 + b * T_ + t - 1] = (float)tag;
        }
    }
}

extern "C" void kernel_launch(void* const* d_in, const int* in_sizes, int n_in,
                              void* d_out, int out_size, void* d_ws, size_t ws_size,
                              hipStream_t stream) {
    const int* us = (const int*)d_in[0];
    const int* ls = (const int*)d_in[1];
    const float* embed = (const float*)d_in[2];
    const float* Wih0f = (const float*)d_in[3];
    const float* Whh0f = (const float*)d_in[4];
    const float* b0f   = (const float*)d_in[5];
    const float* Wih0b = (const float*)d_in[6];
    const float* Whh0b = (const float*)d_in[7];
    const float* b0b   = (const float*)d_in[8];
    const float* Wih1f = (const float*)d_in[9];
    const float* Whh1f = (const float*)d_in[10];
    const float* b1f   = (const float*)d_in[11];
    const float* Wih1b = (const float*)d_in[12];
    const float* Whh1b = (const float*)d_in[13];
    const float* b1b   = (const float*)d_in[14];
    const float* W1    = (const float*)d_in[15];
    const float* bm1   = (const float*)d_in[16];
    const float* W2    = (const float*)d_in[17];
    const float* bm2   = (const float*)d_in[18];
    const float* trans = (const float*)d_in[19];
    const float* startT= (const float*)d_in[20];
    const float* endT  = (const float*)d_in[21];
    float* out = (float*)d_out;

    char* p = (char*)d_ws;
    auto alloc = [&](size_t bytes) {
        char* r = p;
        p += (bytes + 255) & ~(size_t)255;
        return r;
    };
    ushort* xspH = (ushort*)alloc((size_t)MTOT * E_ * 2);     // 16.8 MB
    ushort* xspL = (ushort*)alloc((size_t)MTOT * E_ * 2);
    ushort* h0spH = (ushort*)alloc((size_t)MTOT * KP1 * 2);   // 79.7 MB
    ushort* h0spL = (ushort*)alloc((size_t)MTOT * KP1 * 2);
    ushort* w0hf = (ushort*)alloc((size_t)NP * E_ * 2);
    ushort* w0lf = (ushort*)alloc((size_t)NP * E_ * 2);
    ushort* w0hb = (ushort*)alloc((size_t)NP * E_ * 2);
    ushort* w0lb = (ushort*)alloc((size_t)NP * E_ * 2);
    ushort* w1hf = (ushort*)alloc((size_t)NP * KP1 * 2);
    ushort* w1lf = (ushort*)alloc((size_t)NP * KP1 * 2);
    ushort* w1hb = (ushort*)alloc((size_t)NP * KP1 * 2);
    ushort* w1lb = (ushort*)alloc((size_t)NP * KP1 * 2);
    float* states = (float*)alloc((size_t)6 * H_ * 64 * 4);
    float* Wc  = (float*)alloc(4800 * 4);
    float* bc  = (float*)alloc(4 * 4);
    float* ysb = (float*)alloc((size_t)B_ * T_ * 4 * 4);
    float* llb = (float*)alloc(64 * 4);

    size_t used = (size_t)(p - (char*)d_ws);
    size_t perTc = (size_t)2 * G4 * 64 * 4 + (size_t)2 * H_ * 64 * 4;
    int Tc = 128;
    while (Tc > 8 && used + (size_t)Tc * perTc + 4096 > ws_size) Tc >>= 1;
    float* preF = (float*)alloc((size_t)G4 * Tc * 64 * 4);
    float* preB = (float*)alloc((size_t)G4 * Tc * 64 * 4);
    float* h1fC = (float*)alloc((size_t)H_ * Tc * 64 * 4);
    float* h1bC = (float*)alloc((size_t)H_ * Tc * 64 * 4);
    int nc = T_ / Tc;
    int chunkRows = Tc * 64;

    xsplit<<<MTOT, 256, 0, stream>>>(us, embed, xspH, xspL);
    wsplit<<<dim3(NP, 1, 2), 256, 0, stream>>>(Wih0f, Wih0b, E_, E_, w0hf, w0lf, w0hb, w0lb);
    wsplit<<<dim3(NP, 1, 2), 256, 0, stream>>>(Wih1f, Wih1b, 1200, KP1, w1hf, w1lf, w1hb, w1lb);
    padzero<<<(MTOT * 16) / 256, 256, 0, stream>>>(h0spH, h0spL);
    wc_kernel<<<19, 256, 0, stream>>>(W1, bm1, W2, bm2, Wc, bc);
    zero_kernel<<<(B_ * T_ * 4 + 255) / 256, 256, 0, stream>>>(ysb, B_ * T_ * 4);

    float* hA_f = states + 0 * 38400;
    float* hB_f = states + 1 * 38400;
    float* c_f  = states + 2 * 38400;
    float* hA_b = states + 3 * 38400;
    float* hB_b = states + 4 * 38400;
    float* c_b  = states + 5 * 38400;

    for (int layer = 0; layer < 2; ++layer) {
        int Kp = layer ? KP1 : E_;
        const ushort* aH = layer ? h0spH : xspH;
        const ushort* aL = layer ? h0spL : xspL;
        const ushort* WhFh = layer ? w1hf : w0hf;
        const ushort* WhFl = layer ? w1lf : w0lf;
        const ushort* WhBh = layer ? w1hb : w0hb;
        const ushort* WhBl = layer ? w1lb : w0lb;
        const float* WhF = layer ? Whh1f : Whh0f;
        const float* WhB = layer ? Whh1b : Whh0b;
        const float* bF  = layer ? b1f : b0f;
        const float* bB  = layer ? b1b : b0b;

        zero_kernel<<<(6 * H_ * 64 + 255) / 256, 256, 0, stream>>>(states, 6 * H_ * 64);

        for (int c = 0; c < nc; ++c) {
            int moffF = c * Tc * 64;
            int moffB = (T_ - (c + 1) * Tc) * 64;
            dim3 gg(NP / 128, chunkRows / 128, 2);
            gemm_mfma<<<gg, 256, 0, stream>>>(WhFh, WhFl, WhBh, WhBl, aH, aL,
                                              Kp, moffF, moffB, preF, preB, chunkRows);
            for (int s = 0; s < Tc; ++s) {
                int step = c * Tc + s;
                int par = step & 1;
                float* outF; int colF; float* outB; int colB; int oldd;
                ushort* spH; ushort* spL;
                if (layer == 0) {
                    outF = nullptr; colF = step * 64;
                    outB = nullptr; colB = (T_ - 1 - step) * 64;
                    oldd = 0; spH = h0spH; spL = h0spL;
                } else {
                    outF = h1fC;    colF = s * 64;
                    outB = h1bC;    colB = (Tc - 1 - s) * 64;
                    oldd = chunkRows; spH = nullptr; spL = nullptr;
                }
                lstm_step<<<300, 256, 0, stream>>>(
                    preF, preB, chunkRows, s, Tc - 1 - s,
                    WhF, WhB, bF, bB,
                    par ? hB_f : hA_f, par ? hA_f : hB_f, c_f,
                    par ? hB_b : hA_b, par ? hA_b : hB_b, c_b,
                    outF, colF, outB, colB, oldd, spH, spL);
            }
            if (layer == 1) {
                emis_add<<<Tc, 256, 0, stream>>>(h1fC, chunkRows, Wc, bc, 1, ysb, c * Tc);
                emis_add<<<Tc, 256, 0, stream>>>(h1bC, chunkRows, Wc + 600 * 4, bc, 0, ysb,
                                                 T_ - (c + 1) * Tc);
            }
        }
    }

    crf_fwd<<<B_, 64, 0, stream>>>(ysb, ls, trans, startT, endT, llb);
    final_loss<<<1, 64, 0, stream>>>(llb, out);
    viterbi<<<B_, 64, 0, stream>>>(ysb, trans, startT, endT, out);
}